// Round 4
// baseline (538.935 us; speedup 1.0000x reference)
//
#include <hip/hip_runtime.h>
#include <hip/hip_cooperative_groups.h>
#include <math.h>

namespace cg = cooperative_groups;

#define BB 32
#define DD 512
#define MM 1024
#define NN 1024

typedef float f32x4 __attribute__((ext_vector_type(4)));
typedef _Float16 f16x8 __attribute__((ext_vector_type(8)));

// Storage plan (P region of d_out, 32768 slots x 4096 B):
//   lower 2048 B of slot s : u16 K row s (GEMM writes; sinkhorn reads once)
//   upper 2048 B of slot s : f16 transposed embeddings (dead after GEMM);
//                            slots 0..2047's upper halves are then reused by
//                            the coop kernel as 2 ping-pong colsum-partial
//                            buffers (2 x 512K floats); everything is finally
//                            overwritten by fp32 P.
// K format: u16 fixed point, raw = round(K*65535), K in ~[0.29,0.47].

// upper-half float accessor: linear float index L -> address in P region
#define UPPER(base, L) ((base) + (((size_t)((L) >> 9)) << 10) + 512 + ((L) & 511))

// ---------------------------------------------------------------------------
// Kernel 1 (prep): transpose+convert embeddings fp32 (b,d,m) -> f16 (b,m,d)
// packed in upper half-slots; column norms; v init; colsum zero.
// ---------------------------------------------------------------------------
__global__ __launch_bounds__(256)
void prep_kernel(const float* __restrict__ srcE, const float* __restrict__ tgtE,
                 float* __restrict__ w1, float* __restrict__ w2,
                 float* __restrict__ v, float* __restrict__ colsum,
                 float* __restrict__ Pout)
{
    __shared__ float T[64][65];
    __shared__ float nsum[64];
    const int mc  = blockIdx.x;        // 0..15
    const int mat = blockIdx.y;        // 0: src, 1: tgt
    const int b   = blockIdx.z;        // 0..31
    const int tid = threadIdx.x;
    const float* E = mat ? tgtE : srcE;
    float* w = mat ? w2 : w1;

    if (tid < 64) nsum[tid] = 0.f;
    if (mat == 0 && tid < 64) {
        const int idx = ((b << 4) + mc) * 64 + tid;   // unique 0..32767
        v[idx] = 1.0f / 1024.0f;
        colsum[idx] = 0.0f;            // ws is poisoned 0xAA each call
    }

    const int m4  = (tid & 15) * 4;
    const int din = tid >> 4;
    const int m0g = mc * 64;
    const float* Eb = E + (size_t)b * (DD * MM) + m0g;

    const int row = tid >> 2;
    const int dc4 = tid & 3;
    const int Rrow = mat * 32768 + b * 1024 + m0g + row;
    char* obase = (char*)Pout + (((size_t)(Rrow >> 1)) << 12) + 2048
                + ((size_t)(Rrow & 1) << 10);

    float nacc[4] = {0.f, 0.f, 0.f, 0.f};

    for (int p = 0; p < 8; ++p) {
        const int d0 = p * 64;
        __syncthreads();
        float4 ld[4];
        #pragma unroll
        for (int s = 0; s < 4; ++s) {
            const int d = d0 + din + 16 * s;
            ld[s] = *reinterpret_cast<const float4*>(Eb + (size_t)d * MM + m4);
        }
        #pragma unroll
        for (int s = 0; s < 4; ++s) {
            nacc[0] = fmaf(ld[s].x, ld[s].x, nacc[0]);
            nacc[1] = fmaf(ld[s].y, ld[s].y, nacc[1]);
            nacc[2] = fmaf(ld[s].z, ld[s].z, nacc[2]);
            nacc[3] = fmaf(ld[s].w, ld[s].w, nacc[3]);
            *reinterpret_cast<float4*>(&T[din + 16 * s][m4]) = ld[s];
        }
        __syncthreads();
        __attribute__((aligned(16))) _Float16 h[16];
        #pragma unroll
        for (int k = 0; k < 16; ++k) h[k] = (_Float16)T[dc4 * 16 + k][row];
        *reinterpret_cast<f16x8*>(obase + (size_t)(d0 + dc4 * 16) * 2)
            = *reinterpret_cast<f16x8*>(&h[0]);
        *reinterpret_cast<f16x8*>(obase + (size_t)(d0 + dc4 * 16 + 8) * 2)
            = *reinterpret_cast<f16x8*>(&h[8]);
    }
    #pragma unroll
    for (int q = 0; q < 4; ++q) atomicAdd(&nsum[m4 + q], nacc[q]);
    __syncthreads();
    if (tid < 64) w[b * 1024 + m0g + tid] = sqrtf(nsum[tid]);
}

// ---------------------------------------------------------------------------
// Kernel 2: fp16 MFMA GEMM, 2-phase pipeline with global_load_lds staging.
// (unchanged from R2, proven)
// ---------------------------------------------------------------------------
__global__ __launch_bounds__(256)
void gemm_kexp_kernel(const float* __restrict__ w1, const float* __restrict__ w2,
                      const float* __restrict__ lp, float* __restrict__ Kout)
{
    __shared__ _Float16 As[2][8192];
    __shared__ _Float16 Bs[2][8192];

    const int tid  = threadIdx.x;
    const int lane = tid & 63;
    const int wave = tid >> 6;
    const int m0 = blockIdx.x * 128;
    const int n0 = blockIdx.y * 128;
    const int b  = blockIdx.z;
    const int wm = (wave & 1) * 64;
    const int wn = (wave >> 1) * 64;
    const int m16  = lane & 15;
    const int quad = lane >> 4;

    const char* pbase = (const char*)Kout;
    const char* srcA[4]; const char* srcB[4];
    #pragma unroll
    for (int c = 0; c < 4; ++c) {
        const int idx  = (wave * 4 + c) * 64 + lane;
        const int m    = idx >> 3;
        const int kg   = idx & 7;
        const int colb = ((kg ^ (m & 7)) << 4);
        const int Ra = b * 1024 + m0 + m;
        srcA[c] = pbase + (((size_t)(Ra >> 1)) << 12) + 2048
                + ((size_t)(Ra & 1) << 10) + colb;
        const int Rb = 32768 + b * 1024 + n0 + m;
        srcB[c] = pbase + (((size_t)(Rb >> 1)) << 12) + 2048
                + ((size_t)(Rb & 1) << 10) + colb;
    }

    f32x4 acc[4][4];
    #pragma unroll
    for (int i = 0; i < 4; ++i)
        #pragma unroll
        for (int j = 0; j < 4; ++j)
            acc[i][j] = (f32x4){0.f, 0.f, 0.f, 0.f};

    auto stage = [&](int buf, int kt_) {
        const int kb = kt_ * 128;
        #pragma unroll
        for (int c = 0; c < 4; ++c) {
            __builtin_amdgcn_global_load_lds(
                (const __attribute__((address_space(1))) unsigned int*)(srcA[c] + kb),
                (__attribute__((address_space(3))) unsigned int*)&As[buf][(wave * 4 + c) * 512],
                16, 0, 0);
            __builtin_amdgcn_global_load_lds(
                (const __attribute__((address_space(1))) unsigned int*)(srcB[c] + kb),
                (__attribute__((address_space(3))) unsigned int*)&Bs[buf][(wave * 4 + c) * 512],
                16, 0, 0);
        }
    };

    stage(0, 0);
    __syncthreads();
    int cur = 0;
    for (int kt = 0; kt < 8; ++kt) {
        if (kt < 7) stage(cur ^ 1, kt + 1);
        #pragma unroll
        for (int ks = 0; ks < 2; ++ks) {
            const int kg = ks * 4 + quad;
            f16x8 af[4], bfr[4];
            #pragma unroll
            for (int i = 0; i < 4; ++i) {
                const int rm = wm + i * 16 + m16;
                af[i]  = *reinterpret_cast<const f16x8*>(&As[cur][rm * 64 + ((kg ^ (rm & 7)) << 3)]);
                const int rn = wn + i * 16 + m16;
                bfr[i] = *reinterpret_cast<const f16x8*>(&Bs[cur][rn * 64 + ((kg ^ (rn & 7)) << 3)]);
            }
            #pragma unroll
            for (int i = 0; i < 4; ++i)
                #pragma unroll
                for (int j = 0; j < 4; ++j)
                    acc[i][j] = __builtin_amdgcn_mfma_f32_16x16x32_f16(af[i], bfr[j], acc[i][j], 0, 0, 0);
        }
        __syncthreads();
        cur ^= 1;
    }

    const float inv_l = 1.0f / fmaxf(lp[0], 1e-8f);
    float w2v[4];
    #pragma unroll
    for (int j = 0; j < 4; ++j) w2v[j] = w2[b * NN + n0 + wn + j * 16 + m16];
    unsigned short* Ls = (unsigned short*)&As[0][0];
    #pragma unroll
    for (int i = 0; i < 4; ++i) {
        #pragma unroll
        for (int r = 0; r < 4; ++r) {
            const int m = wm + i * 16 + quad * 4 + r;
            const float w1v = w1[b * MM + m0 + m];
            #pragma unroll
            for (int j = 0; j < 4; ++j) {
                const float dot = acc[i][j][r];
                const float den = fmaxf(w1v * w2v[j], 1e-6f);
                const float kv  = __expf((dot / den - 1.0f) * inv_l);
                const int n = wn + j * 16 + m16;
                const int sidx = m * 128 + ((((n >> 3) ^ (m & 7)) << 3) | (n & 7));
                Ls[sidx] = (unsigned short)fminf(fmaf(kv, 65535.0f, 0.5f), 65535.0f);
            }
        }
    }
    __syncthreads();
    const int row = tid >> 1, half = tid & 1;
    char* orow = (char*)Kout + ((size_t)(b * 1024 + m0 + row) << 12)
               + (size_t)n0 * 2 + half * 128;
    #pragma unroll
    for (int c = 0; c < 8; ++c) {
        const int g = half * 8 + c;
        const uint4 val = *reinterpret_cast<const uint4*>(
            &Ls[row * 128 + ((g ^ (row & 7)) << 3)]);
        reinterpret_cast<uint4*>(orow)[c] = val;
    }
}

// ---------------------------------------------------------------------------
// Kernel 3 (cooperative): Sinkhorn x5 + P + row sums + weighted_ref,
// K register-resident. 512 blocks x 256 threads (launch_bounds(256,2)).
// Colsum partials: ping-pong buffers in dead-emb upper half-slots; each
// block writes its 1024 partials coalesced; after ONE grid.sync per
// iteration every block sums the 16 mc-partials for its own columns and
// applies the powf itself (no atomics, no zeroing, no serial phase).
// ---------------------------------------------------------------------------
__global__ __launch_bounds__(256, 2)
void sinkhorn_p_kernel(float* __restrict__ Kmat, const float* __restrict__ tgt,
                       float* __restrict__ rowb, float* __restrict__ wref,
                       const float* __restrict__ lp, const float* __restrict__ rp)
{
    cg::grid_group grid = cg::this_grid();
    const int blk = blockIdx.x;          // 0..511
    const int b   = blk >> 4;            // 0..31
    const int mc  = blk & 15;            // 0..15
    const int wv  = threadIdx.x >> 6, lane = threadIdx.x & 63;
    const float l = lp[0], rho = rp[0];
    const float fi = rho / fmaxf(rho + l, 1e-8f);
    const int m0   = mc * 64 + wv * 16;
    const int gid0 = (b << 10) + m0;

    // ---- load 16 rows of u16 K into registers (static indexing only) ----
    uint4 ku[16][2];
    #pragma unroll
    for (int r = 0; r < 16; ++r) {
        const uint4* kr = (const uint4*)((const char*)Kmat + ((size_t)(gid0 + r) << 12));
        ku[r][0] = kr[lane];           // cols [8*lane, +8)
        ku[r][1] = kr[64 + lane];      // cols [512+8*lane, +8)
    }

    __shared__ float red[4][1024];
    float um[16];
    float vvs[16];   // v for this lane's cols: j<8 -> 8*lane+j ; j>=8 -> 512+8*lane+(j-8)

    for (int it = 0; it < 5; ++it) {
        if (it == 0) {
            #pragma unroll
            for (int j = 0; j < 16; ++j) vvs[j] = 1.0f / 1024.0f;
        } else {
            const int X = (it - 1) & 1;
            const int base = X * 524288 + (b << 10);
            float sm[16];
            #pragma unroll
            for (int j = 0; j < 16; ++j) sm[j] = 0.f;
            #pragma unroll
            for (int m = 0; m < 16; ++m) {
                const int Lb = base + m * 32768;
                const float4 a0 = *reinterpret_cast<const float4*>(UPPER(Kmat, Lb + 8 * lane));
                const float4 a1 = *reinterpret_cast<const float4*>(UPPER(Kmat, Lb + 8 * lane + 4));
                const float4 a2 = *reinterpret_cast<const float4*>(UPPER(Kmat, Lb + 512 + 8 * lane));
                const float4 a3 = *reinterpret_cast<const float4*>(UPPER(Kmat, Lb + 512 + 8 * lane + 4));
                sm[0] += a0.x;  sm[1] += a0.y;  sm[2]  += a0.z;  sm[3]  += a0.w;
                sm[4] += a1.x;  sm[5] += a1.y;  sm[6]  += a1.z;  sm[7]  += a1.w;
                sm[8] += a2.x;  sm[9] += a2.y;  sm[10] += a2.z;  sm[11] += a2.w;
                sm[12] += a3.x; sm[13] += a3.y; sm[14] += a3.z;  sm[15] += a3.w;
            }
            #pragma unroll
            for (int j = 0; j < 16; ++j)
                vvs[j] = __powf((1.0f / 1024.0f) / fmaxf(sm[j] * (1.0f / 65535.0f), 1e-8f), fi);
        }

        // ---- row dots (raw x65535 scale) ----
        float s[16];
        #pragma unroll
        for (int r = 0; r < 16; ++r) {
            float t = 0.f;
            #pragma unroll
            for (int c = 0; c < 2; ++c) {
                const uint4 q = ku[r][c];
                t = fmaf((float)(q.x & 0xffffu), vvs[8 * c + 0], t);
                t = fmaf((float)(q.x >> 16),     vvs[8 * c + 1], t);
                t = fmaf((float)(q.y & 0xffffu), vvs[8 * c + 2], t);
                t = fmaf((float)(q.y >> 16),     vvs[8 * c + 3], t);
                t = fmaf((float)(q.z & 0xffffu), vvs[8 * c + 4], t);
                t = fmaf((float)(q.z >> 16),     vvs[8 * c + 5], t);
                t = fmaf((float)(q.w & 0xffffu), vvs[8 * c + 6], t);
                t = fmaf((float)(q.w >> 16),     vvs[8 * c + 7], t);
            }
            s[r] = t;
        }
        #pragma unroll
        for (int off = 32; off > 0; off >>= 1)
            #pragma unroll
            for (int r = 0; r < 16; ++r) s[r] += __shfl_down(s[r], off);
        #pragma unroll
        for (int r = 0; r < 16; ++r) {
            const float sv = __builtin_amdgcn_readfirstlane(s[r]) * (1.0f / 65535.0f);
            um[r] = __powf((1.0f / 1024.0f) / fmaxf(sv, 1e-8f), fi);
        }

        // ---- colsum partials (raw scale) ----
        float cacc[16];
        #pragma unroll
        for (int j = 0; j < 16; ++j) cacc[j] = 0.f;
        #pragma unroll
        for (int r = 0; r < 16; ++r) {
            const float umr = um[r];
            #pragma unroll
            for (int c = 0; c < 2; ++c) {
                const uint4 q = ku[r][c];
                float* cc = &cacc[8 * c];
                cc[0] = fmaf((float)(q.x & 0xffffu), umr, cc[0]);
                cc[1] = fmaf((float)(q.x >> 16),     umr, cc[1]);
                cc[2] = fmaf((float)(q.y & 0xffffu), umr, cc[2]);
                cc[3] = fmaf((float)(q.y >> 16),     umr, cc[3]);
                cc[4] = fmaf((float)(q.z & 0xffffu), umr, cc[4]);
                cc[5] = fmaf((float)(q.z >> 16),     umr, cc[5]);
                cc[6] = fmaf((float)(q.w & 0xffffu), umr, cc[6]);
                cc[7] = fmaf((float)(q.w >> 16),     umr, cc[7]);
            }
        }
        __syncthreads();
        *reinterpret_cast<float4*>(&red[wv][8 * lane])           = make_float4(cacc[0],  cacc[1],  cacc[2],  cacc[3]);
        *reinterpret_cast<float4*>(&red[wv][8 * lane + 4])       = make_float4(cacc[4],  cacc[5],  cacc[6],  cacc[7]);
        *reinterpret_cast<float4*>(&red[wv][512 + 8 * lane])     = make_float4(cacc[8],  cacc[9],  cacc[10], cacc[11]);
        *reinterpret_cast<float4*>(&red[wv][512 + 8 * lane + 4]) = make_float4(cacc[12], cacc[13], cacc[14], cacc[15]);
        __syncthreads();
        const int t = threadIdx.x;
        float4 s4 = *reinterpret_cast<const float4*>(&red[0][4 * t]);
        #pragma unroll
        for (int w = 1; w < 4; ++w) {
            const float4 rw = *reinterpret_cast<const float4*>(&red[w][4 * t]);
            s4.x += rw.x; s4.y += rw.y; s4.z += rw.z; s4.w += rw.w;
        }
        const int Lw = (it & 1) * 524288 + mc * 32768 + (b << 10) + 4 * t;
        *reinterpret_cast<float4*>(UPPER(Kmat, Lw)) = s4;
        __threadfence();
        grid.sync();
    }

    // ---- final v (it=4 wrote buffer X = 0) ----
    {
        const int base = (b << 10);      // X = 0
        float sm[16];
        #pragma unroll
        for (int j = 0; j < 16; ++j) sm[j] = 0.f;
        #pragma unroll
        for (int m = 0; m < 16; ++m) {
            const int Lb = base + m * 32768;
            const float4 a0 = *reinterpret_cast<const float4*>(UPPER(Kmat, Lb + 8 * lane));
            const float4 a1 = *reinterpret_cast<const float4*>(UPPER(Kmat, Lb + 8 * lane + 4));
            const float4 a2 = *reinterpret_cast<const float4*>(UPPER(Kmat, Lb + 512 + 8 * lane));
            const float4 a3 = *reinterpret_cast<const float4*>(UPPER(Kmat, Lb + 512 + 8 * lane + 4));
            sm[0] += a0.x;  sm[1] += a0.y;  sm[2]  += a0.z;  sm[3]  += a0.w;
            sm[4] += a1.x;  sm[5] += a1.y;  sm[6]  += a1.z;  sm[7]  += a1.w;
            sm[8] += a2.x;  sm[9] += a2.y;  sm[10] += a2.z;  sm[11] += a2.w;
            sm[12] += a3.x; sm[13] += a3.y; sm[14] += a3.z;  sm[15] += a3.w;
        }
        #pragma unroll
        for (int j = 0; j < 16; ++j)
            vvs[j] = __powf((1.0f / 1024.0f) / fmaxf(sm[j] * (1.0f / 65535.0f), 1e-8f), fi);
    }
    grid.sync();                         // partial reads done before P overwrites

    // ---- P phase: P = u*K*v in-place, row sums, weighted_ref ----
    const float4* tb = (const float4*)(tgt + (size_t)b * 3072);
    float4 txa[4], tya[4], tza[4];
    txa[0] = tb[2 * lane];        txa[1] = tb[2 * lane + 1];
    txa[2] = tb[128 + 2 * lane];  txa[3] = tb[129 + 2 * lane];
    tya[0] = tb[256 + 2 * lane];  tya[1] = tb[257 + 2 * lane];
    tya[2] = tb[384 + 2 * lane];  tya[3] = tb[385 + 2 * lane];
    tza[0] = tb[512 + 2 * lane];  tza[1] = tb[513 + 2 * lane];
    tza[2] = tb[640 + 2 * lane];  tza[3] = tb[641 + 2 * lane];

    #pragma unroll
    for (int r = 0; r < 16; ++r) {
        float4* prow = (float4*)((char*)Kmat + ((size_t)(gid0 + r) << 12));
        const float um_s = um[r] * (1.0f / 65535.0f);
        float s = 0.f, x = 0.f, y = 0.f, z = 0.f;
        #pragma unroll
        for (int c = 0; c < 2; ++c) {
            const uint4 q = ku[r][c];
            float4 pa, pb;
            pa.x = um_s * (float)(q.x & 0xffffu) * vvs[8 * c + 0];
            pa.y = um_s * (float)(q.x >> 16)     * vvs[8 * c + 1];
            pa.z = um_s * (float)(q.y & 0xffffu) * vvs[8 * c + 2];
            pa.w = um_s * (float)(q.y >> 16)     * vvs[8 * c + 3];
            pb.x = um_s * (float)(q.z & 0xffffu) * vvs[8 * c + 4];
            pb.y = um_s * (float)(q.z >> 16)     * vvs[8 * c + 5];
            pb.z = um_s * (float)(q.w & 0xffffu) * vvs[8 * c + 6];
            pb.w = um_s * (float)(q.w >> 16)     * vvs[8 * c + 7];
            prow[c * 128 + 2 * lane]     = pa;
            prow[c * 128 + 2 * lane + 1] = pb;
            s += (pa.x + pa.y) + (pa.z + pa.w) + (pb.x + pb.y) + (pb.z + pb.w);
            const float4 x0 = txa[2 * c], x1 = txa[2 * c + 1];
            const float4 y0 = tya[2 * c], y1 = tya[2 * c + 1];
            const float4 z0 = tza[2 * c], z1 = tza[2 * c + 1];
            x = fmaf(pa.x, x0.x, x); x = fmaf(pa.y, x0.y, x);
            x = fmaf(pa.z, x0.z, x); x = fmaf(pa.w, x0.w, x);
            x = fmaf(pb.x, x1.x, x); x = fmaf(pb.y, x1.y, x);
            x = fmaf(pb.z, x1.z, x); x = fmaf(pb.w, x1.w, x);
            y = fmaf(pa.x, y0.x, y); y = fmaf(pa.y, y0.y, y);
            y = fmaf(pa.z, y0.z, y); y = fmaf(pa.w, y0.w, y);
            y = fmaf(pb.x, y1.x, y); y = fmaf(pb.y, y1.y, y);
            y = fmaf(pb.z, y1.z, y); y = fmaf(pb.w, y1.w, y);
            z = fmaf(pa.x, z0.x, z); z = fmaf(pa.y, z0.y, z);
            z = fmaf(pa.z, z0.z, z); z = fmaf(pa.w, z0.w, z);
            z = fmaf(pb.x, z1.x, z); z = fmaf(pb.y, z1.y, z);
            z = fmaf(pb.z, z1.z, z); z = fmaf(pb.w, z1.w, z);
        }
        #pragma unroll
        for (int off = 32; off > 0; off >>= 1) {
            s += __shfl_down(s, off);
            x += __shfl_down(x, off);
            y += __shfl_down(y, off);
            z += __shfl_down(z, off);
        }
        if (lane == 0) {
            rowb[gid0 + r] = s;
            const float inv = 1.0f / (s + 1e-6f);
            wref[(gid0 + r) * 3 + 0] = x * inv;
            wref[(gid0 + r) * 3 + 1] = y * inv;
            wref[(gid0 + r) * 3 + 2] = z * inv;
        }
    }
}

// ---------------------------------------------------------------------------
// FALLBACK kernels (proven in R2), used if the cooperative launch is refused.
// ---------------------------------------------------------------------------
__global__ __launch_bounds__(256)
void uv_fused_kernel(const float* __restrict__ Kmat, const float* __restrict__ v,
                     float* __restrict__ u, float* __restrict__ colsum,
                     const float* __restrict__ lp, const float* __restrict__ rp)
{
    const int ms = blockIdx.x;
    const int b  = blockIdx.y;
    const int wv = threadIdx.x >> 6, lane = threadIdx.x & 63;
    const float l = lp[0], rho = rp[0];
    const float fi = rho / fmaxf(rho + l, 1e-8f);
    const int m0 = ms * 32 + wv * 8;
    const int gid0 = (b << 10) + m0;

    uint4 ku[8][2];
    #pragma unroll
    for (int r = 0; r < 8; ++r) {
        const uint4* kr = (const uint4*)((const char*)Kmat + ((size_t)(gid0 + r) << 12));
        ku[r][0] = kr[lane];
        ku[r][1] = kr[64 + lane];
    }
    const float4* vb4 = (const float4*)(v + (b << 10));
    float4 vv[4];
    vv[0] = vb4[2 * lane];       vv[1] = vb4[2 * lane + 1];
    vv[2] = vb4[128 + 2 * lane]; vv[3] = vb4[129 + 2 * lane];

    float s[8];
    #pragma unroll
    for (int r = 0; r < 8; ++r) {
        float t = 0.f;
        #pragma unroll
        for (int c = 0; c < 2; ++c) {
            const uint4 q = ku[r][c];
            const float4 va = vv[2 * c], vb2 = vv[2 * c + 1];
            t = fmaf((float)(q.x & 0xffffu), va.x, t);
            t = fmaf((float)(q.x >> 16),     va.y, t);
            t = fmaf((float)(q.y & 0xffffu), va.z, t);
            t = fmaf((float)(q.y >> 16),     va.w, t);
            t = fmaf((float)(q.z & 0xffffu), vb2.x, t);
            t = fmaf((float)(q.z >> 16),     vb2.y, t);
            t = fmaf((float)(q.w & 0xffffu), vb2.z, t);
            t = fmaf((float)(q.w >> 16),     vb2.w, t);
        }
        s[r] = t;
    }
    #pragma unroll
    for (int off = 32; off > 0; off >>= 1)
        #pragma unroll
        for (int r = 0; r < 8; ++r) s[r] += __shfl_down(s[r], off);
    float um[8];
    #pragma unroll
    for (int r = 0; r < 8; ++r) {
        const float sv = __builtin_amdgcn_readfirstlane(s[r]) * (1.0f / 65535.0f);
        um[r] = __powf((1.0f / 1024.0f) / fmaxf(sv, 1e-8f), fi);
    }
    if (lane == 0) {
        float* ub = u + (b << 10);
        #pragma unroll
        for (int r = 0; r < 8; ++r) ub[m0 + r] = um[r];
    }

    float cacc[16];
    #pragma unroll
    for (int j = 0; j < 16; ++j) cacc[j] = 0.f;
    #pragma unroll
    for (int r = 0; r < 8; ++r) {
        const float umr = um[r];
        #pragma unroll
        for (int c = 0; c < 2; ++c) {
            const uint4 q = ku[r][c];
            float* cc = &cacc[8 * c];
            cc[0] = fmaf((float)(q.x & 0xffffu), umr, cc[0]);
            cc[1] = fmaf((float)(q.x >> 16),     umr, cc[1]);
            cc[2] = fmaf((float)(q.y & 0xffffu), umr, cc[2]);
            cc[3] = fmaf((float)(q.y >> 16),     umr, cc[3]);
            cc[4] = fmaf((float)(q.z & 0xffffu), umr, cc[4]);
            cc[5] = fmaf((float)(q.z >> 16),     umr, cc[5]);
            cc[6] = fmaf((float)(q.w & 0xffffu), umr, cc[6]);
            cc[7] = fmaf((float)(q.w >> 16),     umr, cc[7]);
        }
    }
    __shared__ float red[4][1024];
    *reinterpret_cast<float4*>(&red[wv][8 * lane])           = make_float4(cacc[0],  cacc[1],  cacc[2],  cacc[3]);
    *reinterpret_cast<float4*>(&red[wv][8 * lane + 4])       = make_float4(cacc[4],  cacc[5],  cacc[6],  cacc[7]);
    *reinterpret_cast<float4*>(&red[wv][512 + 8 * lane])     = make_float4(cacc[8],  cacc[9],  cacc[10], cacc[11]);
    *reinterpret_cast<float4*>(&red[wv][512 + 8 * lane + 4]) = make_float4(cacc[12], cacc[13], cacc[14], cacc[15]);
    __syncthreads();
    const int t = threadIdx.x;
    float4 s4 = *reinterpret_cast<const float4*>(&red[0][4 * t]);
    #pragma unroll
    for (int w = 1; w < 4; ++w) {
        const float4 rw = *reinterpret_cast<const float4*>(&red[w][4 * t]);
        s4.x += rw.x; s4.y += rw.y; s4.z += rw.z; s4.w += rw.w;
    }
    float* cs = colsum + (b << 10) + 4 * t;
    atomicAdd(cs + 0, s4.x);
    atomicAdd(cs + 1, s4.y);
    atomicAdd(cs + 2, s4.z);
    atomicAdd(cs + 3, s4.w);
}

__global__ __launch_bounds__(256)
void v_finalize_kernel(float* __restrict__ colsum, float* __restrict__ v,
                       const float* __restrict__ lp, const float* __restrict__ rp)
{
    const int idx = blockIdx.x * 256 + threadIdx.x;
    const float s = colsum[idx] * (1.0f / 65535.0f);
    colsum[idx] = 0.0f;
    const float l = lp[0], rho = rp[0];
    const float fi = rho / fmaxf(rho + l, 1e-8f);
    v[idx] = __powf((1.0f / 1024.0f) / fmaxf(s, 1e-8f), fi);
}

__global__ __launch_bounds__(256)
void p_pass_kernel(float* __restrict__ Kmat, const float* __restrict__ u,
                   const float* __restrict__ v, const float* __restrict__ tgt,
                   float* __restrict__ rowb, float* __restrict__ wref)
{
    const int gid  = (blockIdx.x * 256 + threadIdx.x) >> 6;
    const int lane = threadIdx.x & 63;
    const int b = gid >> 10;
    char* rowbase = (char*)Kmat + ((size_t)gid << 12);
    const uint4* kr = (const uint4*)rowbase;
    uint4 ku[2];
    ku[0] = kr[lane];
    ku[1] = kr[64 + lane];
    const float4* vb = (const float4*)(v + (b << 10));
    const float4* tb = (const float4*)(tgt + (size_t)b * 3072);
    const float um_s = u[gid] * (1.0f / 65535.0f);
    float4 vv[4], txa[4], tya[4], tza[4];
    vv[0]  = vb[2 * lane];        vv[1]  = vb[2 * lane + 1];
    vv[2]  = vb[128 + 2 * lane];  vv[3]  = vb[129 + 2 * lane];
    txa[0] = tb[2 * lane];        txa[1] = tb[2 * lane + 1];
    txa[2] = tb[128 + 2 * lane];  txa[3] = tb[129 + 2 * lane];
    tya[0] = tb[256 + 2 * lane];  tya[1] = tb[257 + 2 * lane];
    tya[2] = tb[384 + 2 * lane];  tya[3] = tb[385 + 2 * lane];
    tza[0] = tb[512 + 2 * lane];  tza[1] = tb[513 + 2 * lane];
    tza[2] = tb[640 + 2 * lane];  tza[3] = tb[641 + 2 * lane];
    asm volatile("s_waitcnt vmcnt(0)" ::: "memory");
    float4* prow = (float4*)rowbase;
    float s = 0.f, x = 0.f, y = 0.f, z = 0.f;
    #pragma unroll
    for (int c = 0; c < 2; ++c) {
        const uint4 q = ku[c];
        const float k0 = (float)(q.x & 0xffffu), k1 = (float)(q.x >> 16);
        const float k2 = (float)(q.y & 0xffffu), k3 = (float)(q.y >> 16);
        const float k4 = (float)(q.z & 0xffffu), k5 = (float)(q.z >> 16);
        const float k6 = (float)(q.w & 0xffffu), k7 = (float)(q.w >> 16);
        const float4 va = vv[2 * c], vb2 = vv[2 * c + 1];
        float4 pa, pb;
        pa.x = um_s * k0 * va.x;  pa.y = um_s * k1 * va.y;
        pa.z = um_s * k2 * va.z;  pa.w = um_s * k3 * va.w;
        pb.x = um_s * k4 * vb2.x; pb.y = um_s * k5 * vb2.y;
        pb.z = um_s * k6 * vb2.z; pb.w = um_s * k7 * vb2.w;
        prow[c * 128 + 2 * lane]     = pa;
        prow[c * 128 + 2 * lane + 1] = pb;
        s += (pa.x + pa.y) + (pa.z + pa.w) + (pb.x + pb.y) + (pb.z + pb.w);
        const float4 x0 = txa[2 * c], x1 = txa[2 * c + 1];
        const float4 y0 = tya[2 * c], y1 = tya[2 * c + 1];
        const float4 z0 = tza[2 * c], z1 = tza[2 * c + 1];
        x = fmaf(pa.x, x0.x, x); x = fmaf(pa.y, x0.y, x);
        x = fmaf(pa.z, x0.z, x); x = fmaf(pa.w, x0.w, x);
        x = fmaf(pb.x, x1.x, x); x = fmaf(pb.y, x1.y, x);
        x = fmaf(pb.z, x1.z, x); x = fmaf(pb.w, x1.w, x);
        y = fmaf(pa.x, y0.x, y); y = fmaf(pa.y, y0.y, y);
        y = fmaf(pa.z, y0.z, y); y = fmaf(pa.w, y0.w, y);
        y = fmaf(pb.x, y1.x, y); y = fmaf(pb.y, y1.y, y);
        y = fmaf(pb.z, y1.z, y); y = fmaf(pb.w, y1.w, y);
        z = fmaf(pa.x, z0.x, z); z = fmaf(pa.y, z0.y, z);
        z = fmaf(pa.z, z0.z, z); z = fmaf(pa.w, z0.w, z);
        z = fmaf(pb.x, z1.x, z); z = fmaf(pb.y, z1.y, z);
        z = fmaf(pb.z, z1.z, z); z = fmaf(pb.w, z1.w, z);
    }
    #pragma unroll
    for (int off = 32; off > 0; off >>= 1) {
        s += __shfl_down(s, off);
        x += __shfl_down(x, off);
        y += __shfl_down(y, off);
        z += __shfl_down(z, off);
    }
    if (lane == 0) {
        rowb[gid] = s;
        const float inv = 1.0f / (s + 1e-6f);
        wref[gid * 3 + 0] = x * inv;
        wref[gid * 3 + 1] = y * inv;
        wref[gid * 3 + 2] = z * inv;
    }
}

// ---------------------------------------------------------------------------
// Kernel 5: per-batch weighted centroids + covariance (one block per batch)
// ---------------------------------------------------------------------------
__device__ __forceinline__ float block_reduce_sum(float x, float* lds4, int wv, int lane)
{
    #pragma unroll
    for (int off = 32; off > 0; off >>= 1) x += __shfl_down(x, off);
    __syncthreads();
    if (lane == 0) lds4[wv] = x;
    __syncthreads();
    return (lds4[0] + lds4[1]) + (lds4[2] + lds4[3]);
}

__global__ __launch_bounds__(256)
void kabsch_stats_kernel(const float* __restrict__ rowb, const float* __restrict__ wref,
                         const float* __restrict__ src, float* __restrict__ cov,
                         float* __restrict__ ca, float* __restrict__ cb)
{
    __shared__ float lds4[4];
    const int b = blockIdx.x, tid = threadIdx.x;
    const int wv = tid >> 6, lane = tid & 63;
    float r[4], w[4], ax[4], ay[4], az[4], bx[4], by[4], bz[4];
    float rsum = 0.f;
    #pragma unroll
    for (int i = 0; i < 4; ++i) {
        const int m = tid + 256 * i;
        r[i] = rowb[(b << 10) + m];
        rsum += r[i];
    }
    const float total = block_reduce_sum(rsum, lds4, wv, lane);
    const float inv = 1.0f / (total + 1e-6f);
    #pragma unroll
    for (int i = 0; i < 4; ++i) {
        const int m = tid + 256 * i;
        w[i]  = r[i] * inv;
        ax[i] = src[b * 3072 + m];
        ay[i] = src[b * 3072 + 1024 + m];
        az[i] = src[b * 3072 + 2048 + m];
        bx[i] = wref[((b << 10) + m) * 3 + 0];
        by[i] = wref[((b << 10) + m) * 3 + 1];
        bz[i] = wref[((b << 10) + m) * 3 + 2];
    }
    float cax = 0, cay = 0, caz = 0, cbx = 0, cby = 0, cbz = 0;
    #pragma unroll
    for (int i = 0; i < 4; ++i) {
        cax = fmaf(ax[i], w[i], cax); cay = fmaf(ay[i], w[i], cay); caz = fmaf(az[i], w[i], caz);
        cbx = fmaf(bx[i], w[i], cbx); cby = fmaf(by[i], w[i], cby); cbz = fmaf(bz[i], w[i], cbz);
    }
    cax = block_reduce_sum(cax, lds4, wv, lane);
    cay = block_reduce_sum(cay, lds4, wv, lane);
    caz = block_reduce_sum(caz, lds4, wv, lane);
    cbx = block_reduce_sum(cbx, lds4, wv, lane);
    cby = block_reduce_sum(cby, lds4, wv, lane);
    cbz = block_reduce_sum(cbz, lds4, wv, lane);
    float c[9] = {0,0,0,0,0,0,0,0,0};
    #pragma unroll
    for (int i = 0; i < 4; ++i) {
        const float dax = ax[i] - cax, day = ay[i] - cay, daz = az[i] - caz;
        const float dbx = (bx[i] - cbx) * w[i];
        const float dby = (by[i] - cby) * w[i];
        const float dbz = (bz[i] - cbz) * w[i];
        c[0] = fmaf(dax, dbx, c[0]); c[1] = fmaf(dax, dby, c[1]); c[2] = fmaf(dax, dbz, c[2]);
        c[3] = fmaf(day, dbx, c[3]); c[4] = fmaf(day, dby, c[4]); c[5] = fmaf(day, dbz, c[5]);
        c[6] = fmaf(daz, dbx, c[6]); c[7] = fmaf(daz, dby, c[7]); c[8] = fmaf(daz, dbz, c[8]);
    }
    #pragma unroll
    for (int k = 0; k < 9; ++k) c[k] = block_reduce_sum(c[k], lds4, wv, lane);
    if (tid == 0) {
        #pragma unroll
        for (int k = 0; k < 9; ++k) cov[b * 9 + k] = c[k];
        ca[b * 3 + 0] = cax; ca[b * 3 + 1] = cay; ca[b * 3 + 2] = caz;
        cb[b * 3 + 0] = cbx; cb[b * 3 + 1] = cby; cb[b * 3 + 2] = cbz;
    }
}

// ---------------------------------------------------------------------------
// Kernel 6: 3x3 SVD (double-precision Jacobi on A^T A) + Kabsch R,t
// ---------------------------------------------------------------------------
__device__ __forceinline__ void jrot_d(double S[3][3], double V[3][3], int p, int q)
{
    const double apq = S[p][q];
    if (fabs(apq) < 1e-300) return;
    const double theta = (S[q][q] - S[p][p]) / (2.0 * apq);
    const double tt = copysign(1.0, theta) / (fabs(theta) + sqrt(1.0 + theta * theta));
    const double c = 1.0 / sqrt(1.0 + tt * tt);
    const double s = tt * c;
    #pragma unroll
    for (int k = 0; k < 3; ++k) {
        const double skp = S[k][p], skq = S[k][q];
        S[k][p] = c * skp - s * skq;
        S[k][q] = s * skp + c * skq;
    }
    #pragma unroll
    for (int k = 0; k < 3; ++k) {
        const double spk = S[p][k], sqk = S[q][k];
        S[p][k] = c * spk - s * sqk;
        S[q][k] = s * spk + c * sqk;
    }
    #pragma unroll
    for (int k = 0; k < 3; ++k) {
        const double vkp = V[k][p], vkq = V[k][q];
        V[k][p] = c * vkp - s * vkq;
        V[k][q] = s * vkp + c * vkq;
    }
}

__global__ __launch_bounds__(64)
void svd_kernel(const float* __restrict__ cov, const float* __restrict__ ca,
                const float* __restrict__ cb, float* __restrict__ out)
{
    const int b = threadIdx.x;
    if (b >= 32) return;
    double A[3][3];
    #pragma unroll
    for (int i = 0; i < 3; ++i)
        #pragma unroll
        for (int j = 0; j < 3; ++j)
            A[i][j] = (double)cov[b * 9 + i * 3 + j];
    double S[3][3];
    #pragma unroll
    for (int i = 0; i < 3; ++i)
        #pragma unroll
        for (int j = 0; j < 3; ++j)
            S[i][j] = A[0][i] * A[0][j] + A[1][i] * A[1][j] + A[2][i] * A[2][j];
    double V[3][3] = {{1,0,0},{0,1,0},{0,0,1}};
    for (int sweep = 0; sweep < 8; ++sweep) {
        jrot_d(S, V, 0, 1);
        jrot_d(S, V, 0, 2);
        jrot_d(S, V, 1, 2);
    }
    int o0 = 0, o1 = 1, o2 = 2;
    double e0 = S[0][0], e1 = S[1][1], e2 = S[2][2];
    double tf; int ti;
    if (e0 < e1) { tf = e0; e0 = e1; e1 = tf; ti = o0; o0 = o1; o1 = ti; }
    if (e0 < e2) { tf = e0; e0 = e2; e2 = tf; ti = o0; o0 = o2; o2 = ti; }
    if (e1 < e2) { tf = e1; e1 = e2; e2 = tf; ti = o1; o1 = o2; o2 = ti; }
    double v1[3] = {V[0][o0], V[1][o0], V[2][o0]};
    double v2[3] = {V[0][o1], V[1][o1], V[2][o1]};
    double v3[3] = {V[0][o2], V[1][o2], V[2][o2]};
    double Av1[3], Av2[3];
    #pragma unroll
    for (int i = 0; i < 3; ++i) {
        Av1[i] = A[i][0] * v1[0] + A[i][1] * v1[1] + A[i][2] * v1[2];
        Av2[i] = A[i][0] * v2[0] + A[i][1] * v2[1] + A[i][2] * v2[2];
    }
    const double n1 = sqrt(Av1[0]*Av1[0] + Av1[1]*Av1[1] + Av1[2]*Av1[2]);
    const double in1 = 1.0 / fmax(n1, 1e-300);
    double u1[3] = {Av1[0]*in1, Av1[1]*in1, Av1[2]*in1};
    const double d12 = Av2[0]*u1[0] + Av2[1]*u1[1] + Av2[2]*u1[2];
    double u2[3] = {Av2[0] - d12*u1[0], Av2[1] - d12*u1[1], Av2[2] - d12*u1[2]};
    const double n2 = sqrt(u2[0]*u2[0] + u2[1]*u2[1] + u2[2]*u2[2]);
    const double in2 = 1.0 / fmax(n2, 1e-300);
    u2[0] *= in2; u2[1] *= in2; u2[2] *= in2;
    double u3[3] = {u1[1]*u2[2] - u1[2]*u2[1],
                    u1[2]*u2[0] - u1[0]*u2[2],
                    u1[0]*u2[1] - u1[1]*u2[0]};
    double R0[3][3];
    #pragma unroll
    for (int i = 0; i < 3; ++i)
        #pragma unroll
        for (int j = 0; j < 3; ++j)
            R0[i][j] = v1[i]*u1[j] + v2[i]*u2[j] + v3[i]*u3[j];
    const double det =
        R0[0][0]*(R0[1][1]*R0[2][2] - R0[1][2]*R0[2][1])
      - R0[0][1]*(R0[1][0]*R0[2][2] - R0[1][2]*R0[2][0])
      + R0[0][2]*(R0[1][0]*R0[2][1] - R0[1][1]*R0[2][0]);
    double Rm[3][3];
    if (det > 0.0) {
        #pragma unroll
        for (int i = 0; i < 3; ++i)
            #pragma unroll
            for (int j = 0; j < 3; ++j)
                Rm[i][j] = R0[i][j];
    } else {
        #pragma unroll
        for (int i = 0; i < 3; ++i)
            #pragma unroll
            for (int j = 0; j < 3; ++j)
                Rm[i][j] = R0[i][j] - 2.0 * v3[i] * u3[j];
    }
    const double cax = (double)ca[b*3+0], cay = (double)ca[b*3+1], caz = (double)ca[b*3+2];
    #pragma unroll
    for (int i = 0; i < 3; ++i)
        #pragma unroll
        for (int j = 0; j < 3; ++j)
            out[b * 9 + i * 3 + j] = (float)Rm[i][j];
    #pragma unroll
    for (int i = 0; i < 3; ++i)
        out[288 + b * 3 + i] = (float)((double)cb[b*3+i] - (Rm[i][0]*cax + Rm[i][1]*cay + Rm[i][2]*caz));
}

// ---------------------------------------------------------------------------
extern "C" void kernel_launch(void* const* d_in, const int* in_sizes, int n_in,
                              void* d_out, int out_size, void* d_ws, size_t ws_size,
                              hipStream_t stream)
{
    const float* srcE = (const float*)d_in[0];
    const float* tgtE = (const float*)d_in[1];
    const float* src  = (const float*)d_in[2];
    const float* tgt  = (const float*)d_in[3];
    const float* lp   = (const float*)d_in[4];
    const float* rp   = (const float*)d_in[5];
    float* out  = (float*)d_out;                 // R(288) | t(96) | P(32M)
    float* Pout = out + 384;

    float* ws     = (float*)d_ws;
    float* w1     = ws;            // 32768
    float* w2     = ws + 32768;    // 32768
    float* u      = ws + 65536;    // 32768 (fallback only)
    float* v      = ws + 98304;    // 32768
    float* rowb   = ws + 131072;   // 32768
    float* wref   = ws + 163840;   // 98304
    float* colsum = ws + 262144;   // 32768
    float* cov    = ws + 294912;   // 288
    float* ca     = ws + 295200;   // 96
    float* cb     = ws + 295296;   // 96

    prep_kernel<<<dim3(16, 2, 32), 256, 0, stream>>>(srcE, tgtE, w1, w2, v, colsum, Pout);
    gemm_kexp_kernel<<<dim3(8, 8, 32), 256, 0, stream>>>(w1, w2, lp, Pout);

    // --- cooperative-capacity gate (computed once, host-only queries) ---
    static int coop_state = -1;     // -1 unknown, 1 usable, 0 fallback
    if (coop_state < 0) {
        int nb = 0, mp = 0, dev = 0;
        (void)hipGetDevice(&dev);
        hipError_t e1 = hipOccupancyMaxActiveBlocksPerMultiprocessor(
            &nb, reinterpret_cast<const void*>(sinkhorn_p_kernel), 256, 0);
        hipError_t e2 = hipDeviceGetAttribute(
            &mp, hipDeviceAttributeMultiprocessorCount, dev);
        coop_state = (e1 == hipSuccess && e2 == hipSuccess && nb * mp >= 512) ? 1 : 0;
        (void)hipGetLastError();
    }

    bool coop_done = false;
    if (coop_state == 1) {
        void* kargs[] = {
            (void*)&Pout, (void*)&tgt, (void*)&rowb, (void*)&wref,
            (void*)&lp, (void*)&rp
        };
        hipError_t e = hipLaunchCooperativeKernel(
            reinterpret_cast<const void*>(sinkhorn_p_kernel),
            dim3(512), dim3(256), kargs, 0, stream);
        if (e == hipSuccess) {
            coop_done = true;
        } else {
            (void)hipGetLastError();   // clear sticky error, take fallback
            coop_state = 0;
        }
    }
    if (!coop_done) {
        for (int it = 0; it < 5; ++it) {
            uv_fused_kernel<<<dim3(32, 32), 256, 0, stream>>>(Pout, v, u, colsum, lp, rp);
            v_finalize_kernel<<<128, 256, 0, stream>>>(colsum, v, lp, rp);
        }
        p_pass_kernel<<<8192, 256, 0, stream>>>(Pout, u, v, tgt, rowb, wref);
    }

    kabsch_stats_kernel<<<32, 256, 0, stream>>>(rowb, wref, src, cov, ca, cb);
    svd_kernel<<<1, 64, 0, stream>>>(cov, ca, cb, out);
}

// Round 5
// 516.727 us; speedup vs baseline: 1.0430x; 1.0430x over previous
//
#include <hip/hip_runtime.h>
#include <math.h>

#define BB 32
#define DD 512
#define MM 1024
#define NN 1024

typedef float f32x4 __attribute__((ext_vector_type(4)));
typedef _Float16 f16x8 __attribute__((ext_vector_type(8)));

// Storage plan (P region of d_out, 32768 slots x 4096 B = 1024 f32 each):
//   lower 2048 B of slot s : u16 K row s (GEMM writes; sink/p_pass read)
//   upper 2048 B of slot s : f16 transposed embeddings (dead after GEMM).
//     Upper halves of slots 0..4095 are then reused as TWO ping-pong
//     colsum-partial buffers (1M floats each): buffer X at linear floats
//     [X*1048576, +1048576), laid out part[ms(32)][b(32)][n(1024)].
//     Launch boundaries are the only synchronization. p_pass finally
//     overwrites every slot with fp32 P.
// K format: u16 fixed point, raw = round(K*65535), K in ~[0.29,0.47].

__device__ __forceinline__ float* upper_ptr(float* base, int L) {
    // linear float index L in the concatenated upper halves -> address
    return base + (((size_t)(L >> 9)) << 10) + 512 + (L & 511);
}

// ---------------------------------------------------------------------------
// Kernel 1 (prep): transpose+convert embeddings fp32 (b,d,m) -> f16 (b,m,d)
// packed in upper half-slots; column norms.
// ---------------------------------------------------------------------------
__global__ __launch_bounds__(256)
void prep_kernel(const float* __restrict__ srcE, const float* __restrict__ tgtE,
                 float* __restrict__ w1, float* __restrict__ w2,
                 float* __restrict__ Pout)
{
    __shared__ float T[64][65];
    __shared__ float nsum[64];
    const int mc  = blockIdx.x;        // 0..15
    const int mat = blockIdx.y;        // 0: src, 1: tgt
    const int b   = blockIdx.z;        // 0..31
    const int tid = threadIdx.x;
    const float* E = mat ? tgtE : srcE;
    float* w = mat ? w2 : w1;

    if (tid < 64) nsum[tid] = 0.f;

    const int m4  = (tid & 15) * 4;
    const int din = tid >> 4;
    const int m0g = mc * 64;
    const float* Eb = E + (size_t)b * (DD * MM) + m0g;

    const int row = tid >> 2;
    const int dc4 = tid & 3;
    const int Rrow = mat * 32768 + b * 1024 + m0g + row;
    char* obase = (char*)Pout + (((size_t)(Rrow >> 1)) << 12) + 2048
                + ((size_t)(Rrow & 1) << 10);

    float nacc[4] = {0.f, 0.f, 0.f, 0.f};

    for (int p = 0; p < 8; ++p) {
        const int d0 = p * 64;
        __syncthreads();
        float4 ld[4];
        #pragma unroll
        for (int s = 0; s < 4; ++s) {
            const int d = d0 + din + 16 * s;
            ld[s] = *reinterpret_cast<const float4*>(Eb + (size_t)d * MM + m4);
        }
        #pragma unroll
        for (int s = 0; s < 4; ++s) {
            nacc[0] = fmaf(ld[s].x, ld[s].x, nacc[0]);
            nacc[1] = fmaf(ld[s].y, ld[s].y, nacc[1]);
            nacc[2] = fmaf(ld[s].z, ld[s].z, nacc[2]);
            nacc[3] = fmaf(ld[s].w, ld[s].w, nacc[3]);
            *reinterpret_cast<float4*>(&T[din + 16 * s][m4]) = ld[s];
        }
        __syncthreads();
        __attribute__((aligned(16))) _Float16 h[16];
        #pragma unroll
        for (int k = 0; k < 16; ++k) h[k] = (_Float16)T[dc4 * 16 + k][row];
        *reinterpret_cast<f16x8*>(obase + (size_t)(d0 + dc4 * 16) * 2)
            = *reinterpret_cast<f16x8*>(&h[0]);
        *reinterpret_cast<f16x8*>(obase + (size_t)(d0 + dc4 * 16 + 8) * 2)
            = *reinterpret_cast<f16x8*>(&h[8]);
    }
    #pragma unroll
    for (int q = 0; q < 4; ++q) atomicAdd(&nsum[m4 + q], nacc[q]);
    __syncthreads();
    if (tid < 64) w[b * 1024 + m0g + tid] = sqrtf(nsum[tid]);
}

// ---------------------------------------------------------------------------
// Kernel 2: fp16 MFMA GEMM, 2-phase pipeline with global_load_lds staging.
// (unchanged from R2, proven)
// ---------------------------------------------------------------------------
__global__ __launch_bounds__(256)
void gemm_kexp_kernel(const float* __restrict__ w1, const float* __restrict__ w2,
                      const float* __restrict__ lp, float* __restrict__ Kout)
{
    __shared__ _Float16 As[2][8192];
    __shared__ _Float16 Bs[2][8192];

    const int tid  = threadIdx.x;
    const int lane = tid & 63;
    const int wave = tid >> 6;
    const int m0 = blockIdx.x * 128;
    const int n0 = blockIdx.y * 128;
    const int b  = blockIdx.z;
    const int wm = (wave & 1) * 64;
    const int wn = (wave >> 1) * 64;
    const int m16  = lane & 15;
    const int quad = lane >> 4;

    const char* pbase = (const char*)Kout;
    const char* srcA[4]; const char* srcB[4];
    #pragma unroll
    for (int c = 0; c < 4; ++c) {
        const int idx  = (wave * 4 + c) * 64 + lane;
        const int m    = idx >> 3;
        const int kg   = idx & 7;
        const int colb = ((kg ^ (m & 7)) << 4);
        const int Ra = b * 1024 + m0 + m;
        srcA[c] = pbase + (((size_t)(Ra >> 1)) << 12) + 2048
                + ((size_t)(Ra & 1) << 10) + colb;
        const int Rb = 32768 + b * 1024 + n0 + m;
        srcB[c] = pbase + (((size_t)(Rb >> 1)) << 12) + 2048
                + ((size_t)(Rb & 1) << 10) + colb;
    }

    f32x4 acc[4][4];
    #pragma unroll
    for (int i = 0; i < 4; ++i)
        #pragma unroll
        for (int j = 0; j < 4; ++j)
            acc[i][j] = (f32x4){0.f, 0.f, 0.f, 0.f};

    auto stage = [&](int buf, int kt_) {
        const int kb = kt_ * 128;
        #pragma unroll
        for (int c = 0; c < 4; ++c) {
            __builtin_amdgcn_global_load_lds(
                (const __attribute__((address_space(1))) unsigned int*)(srcA[c] + kb),
                (__attribute__((address_space(3))) unsigned int*)&As[buf][(wave * 4 + c) * 512],
                16, 0, 0);
            __builtin_amdgcn_global_load_lds(
                (const __attribute__((address_space(1))) unsigned int*)(srcB[c] + kb),
                (__attribute__((address_space(3))) unsigned int*)&Bs[buf][(wave * 4 + c) * 512],
                16, 0, 0);
        }
    };

    stage(0, 0);
    __syncthreads();
    int cur = 0;
    for (int kt = 0; kt < 8; ++kt) {
        if (kt < 7) stage(cur ^ 1, kt + 1);
        #pragma unroll
        for (int ks = 0; ks < 2; ++ks) {
            const int kg = ks * 4 + quad;
            f16x8 af[4], bfr[4];
            #pragma unroll
            for (int i = 0; i < 4; ++i) {
                const int rm = wm + i * 16 + m16;
                af[i]  = *reinterpret_cast<const f16x8*>(&As[cur][rm * 64 + ((kg ^ (rm & 7)) << 3)]);
                const int rn = wn + i * 16 + m16;
                bfr[i] = *reinterpret_cast<const f16x8*>(&Bs[cur][rn * 64 + ((kg ^ (rn & 7)) << 3)]);
            }
            #pragma unroll
            for (int i = 0; i < 4; ++i)
                #pragma unroll
                for (int j = 0; j < 4; ++j)
                    acc[i][j] = __builtin_amdgcn_mfma_f32_16x16x32_f16(af[i], bfr[j], acc[i][j], 0, 0, 0);
        }
        __syncthreads();
        cur ^= 1;
    }

    const float inv_l = 1.0f / fmaxf(lp[0], 1e-8f);
    float w2v[4];
    #pragma unroll
    for (int j = 0; j < 4; ++j) w2v[j] = w2[b * NN + n0 + wn + j * 16 + m16];
    unsigned short* Ls = (unsigned short*)&As[0][0];
    #pragma unroll
    for (int i = 0; i < 4; ++i) {
        #pragma unroll
        for (int r = 0; r < 4; ++r) {
            const int m = wm + i * 16 + quad * 4 + r;
            const float w1v = w1[b * MM + m0 + m];
            #pragma unroll
            for (int j = 0; j < 4; ++j) {
                const float dot = acc[i][j][r];
                const float den = fmaxf(w1v * w2v[j], 1e-6f);
                const float kv  = __expf((dot / den - 1.0f) * inv_l);
                const int n = wn + j * 16 + m16;
                const int sidx = m * 128 + ((((n >> 3) ^ (m & 7)) << 3) | (n & 7));
                Ls[sidx] = (unsigned short)fminf(fmaf(kv, 65535.0f, 0.5f), 65535.0f);
            }
        }
    }
    __syncthreads();
    const int row = tid >> 1, half = tid & 1;
    char* orow = (char*)Kout + ((size_t)(b * 1024 + m0 + row) << 12)
               + (size_t)n0 * 2 + half * 128;
    #pragma unroll
    for (int c = 0; c < 8; ++c) {
        const int g = half * 8 + c;
        const uint4 val = *reinterpret_cast<const uint4*>(
            &Ls[row * 128 + ((g ^ (row & 7)) << 3)]);
        reinterpret_cast<uint4*>(orow)[c] = val;
    }
}

// ---------------------------------------------------------------------------
// Kernel 3 (x5): one Sinkhorn iteration, NO atomics, NO v_finalize launch.
// grid (32 ms, 32 b). Phase A: reduce prev iteration's 32 column-partial
// slices (ping-pong buffer X=(it-1)&1 in the upper half-slots) -> v in LDS
// (4 waves split the 32 slices; 32 KB of loads per block). Phase B: u-dot
// + colsum partials exactly as the proven uv_fused; partials written as
// coalesced float4 to buffer it&1. K row loads issued FIRST so their
// latency hides under phase A.
// ---------------------------------------------------------------------------
__global__ __launch_bounds__(256)
void sink_iter_kernel(float* __restrict__ Pb, float* __restrict__ u,
                      const float* __restrict__ lp, const float* __restrict__ rp,
                      const int it)
{
    const int ms = blockIdx.x;          // 0..31
    const int b  = blockIdx.y;          // 0..31
    const int tid = threadIdx.x;
    const int wv = tid >> 6, lane = tid & 63;
    const float l = lp[0], rho = rp[0];
    const float fi = rho / fmaxf(rho + l, 1e-8f);
    const int m0 = ms * 32 + wv * 8;
    const int gid0 = (b << 10) + m0;

    __shared__ float red[4][1024];
    __shared__ float vlds[1024];

    // ---- issue K row loads first (latency hides under phase A) ----
    uint4 ku[8][2];
    #pragma unroll
    for (int r = 0; r < 8; ++r) {
        const uint4* kr = (const uint4*)((const char*)Pb + ((size_t)(gid0 + r) << 12));
        ku[r][0] = kr[lane];
        ku[r][1] = kr[64 + lane];
    }

    // ---- phase A: v from previous iteration's partials ----
    float4 vv[4];
    if (it == 0) {
        const float iv = 1.0f / 1024.0f;
        vv[0] = vv[1] = vv[2] = vv[3] = make_float4(iv, iv, iv, iv);
    } else {
        const int X = (it - 1) & 1;
        float4 a = make_float4(0.f, 0.f, 0.f, 0.f);
        #pragma unroll
        for (int i = 0; i < 8; ++i) {
            const int msv = wv * 8 + i;
            const float4 p = *reinterpret_cast<const float4*>(
                upper_ptr(Pb, X * 1048576 + msv * 32768 + (b << 10) + 4 * tid));
            a.x += p.x; a.y += p.y; a.z += p.z; a.w += p.w;
        }
        *reinterpret_cast<float4*>(&red[wv][4 * tid]) = a;
        __syncthreads();
        float4 s4 = *reinterpret_cast<const float4*>(&red[0][4 * tid]);
        #pragma unroll
        for (int w = 1; w < 4; ++w) {
            const float4 rw = *reinterpret_cast<const float4*>(&red[w][4 * tid]);
            s4.x += rw.x; s4.y += rw.y; s4.z += rw.z; s4.w += rw.w;
        }
        vlds[4 * tid + 0] = __powf((1.0f / 1024.0f) / fmaxf(s4.x * (1.0f / 65535.0f), 1e-8f), fi);
        vlds[4 * tid + 1] = __powf((1.0f / 1024.0f) / fmaxf(s4.y * (1.0f / 65535.0f), 1e-8f), fi);
        vlds[4 * tid + 2] = __powf((1.0f / 1024.0f) / fmaxf(s4.z * (1.0f / 65535.0f), 1e-8f), fi);
        vlds[4 * tid + 3] = __powf((1.0f / 1024.0f) / fmaxf(s4.w * (1.0f / 65535.0f), 1e-8f), fi);
        __syncthreads();
        vv[0] = *reinterpret_cast<const float4*>(&vlds[8 * lane]);
        vv[1] = *reinterpret_cast<const float4*>(&vlds[8 * lane + 4]);
        vv[2] = *reinterpret_cast<const float4*>(&vlds[512 + 8 * lane]);
        vv[3] = *reinterpret_cast<const float4*>(&vlds[512 + 8 * lane + 4]);
    }

    // ---- phase B: row dots (raw x65535 scale) -> u ----
    float s[8];
    #pragma unroll
    for (int r = 0; r < 8; ++r) {
        float t = 0.f;
        #pragma unroll
        for (int c = 0; c < 2; ++c) {
            const uint4 q = ku[r][c];
            const float4 va = vv[2 * c], vb2 = vv[2 * c + 1];
            t = fmaf((float)(q.x & 0xffffu), va.x, t);
            t = fmaf((float)(q.x >> 16),     va.y, t);
            t = fmaf((float)(q.y & 0xffffu), va.z, t);
            t = fmaf((float)(q.y >> 16),     va.w, t);
            t = fmaf((float)(q.z & 0xffffu), vb2.x, t);
            t = fmaf((float)(q.z >> 16),     vb2.y, t);
            t = fmaf((float)(q.w & 0xffffu), vb2.z, t);
            t = fmaf((float)(q.w >> 16),     vb2.w, t);
        }
        s[r] = t;
    }
    #pragma unroll
    for (int off = 32; off > 0; off >>= 1)
        #pragma unroll
        for (int r = 0; r < 8; ++r) s[r] += __shfl_down(s[r], off);
    float um[8];
    #pragma unroll
    for (int r = 0; r < 8; ++r) {
        const float sv = __builtin_amdgcn_readfirstlane(s[r]) * (1.0f / 65535.0f);
        um[r] = __powf((1.0f / 1024.0f) / fmaxf(sv, 1e-8f), fi);
    }
    if (lane == 0) {
        float* ub = u + (b << 10);
        #pragma unroll
        for (int r = 0; r < 8; ++r) ub[m0 + r] = um[r];
    }

    // ---- colsum partials (raw scale) ----
    float cacc[16];
    #pragma unroll
    for (int j = 0; j < 16; ++j) cacc[j] = 0.f;
    #pragma unroll
    for (int r = 0; r < 8; ++r) {
        const float umr = um[r];
        #pragma unroll
        for (int c = 0; c < 2; ++c) {
            const uint4 q = ku[r][c];
            float* cc = &cacc[8 * c];
            cc[0] = fmaf((float)(q.x & 0xffffu), umr, cc[0]);
            cc[1] = fmaf((float)(q.x >> 16),     umr, cc[1]);
            cc[2] = fmaf((float)(q.y & 0xffffu), umr, cc[2]);
            cc[3] = fmaf((float)(q.y >> 16),     umr, cc[3]);
            cc[4] = fmaf((float)(q.z & 0xffffu), umr, cc[4]);
            cc[5] = fmaf((float)(q.z >> 16),     umr, cc[5]);
            cc[6] = fmaf((float)(q.w & 0xffffu), umr, cc[6]);
            cc[7] = fmaf((float)(q.w >> 16),     umr, cc[7]);
        }
    }
    __syncthreads();                    // red reuse guard (phase A)
    *reinterpret_cast<float4*>(&red[wv][8 * lane])           = make_float4(cacc[0],  cacc[1],  cacc[2],  cacc[3]);
    *reinterpret_cast<float4*>(&red[wv][8 * lane + 4])       = make_float4(cacc[4],  cacc[5],  cacc[6],  cacc[7]);
    *reinterpret_cast<float4*>(&red[wv][512 + 8 * lane])     = make_float4(cacc[8],  cacc[9],  cacc[10], cacc[11]);
    *reinterpret_cast<float4*>(&red[wv][512 + 8 * lane + 4]) = make_float4(cacc[12], cacc[13], cacc[14], cacc[15]);
    __syncthreads();
    float4 s4 = *reinterpret_cast<const float4*>(&red[0][4 * tid]);
    #pragma unroll
    for (int w = 1; w < 4; ++w) {
        const float4 rw = *reinterpret_cast<const float4*>(&red[w][4 * tid]);
        s4.x += rw.x; s4.y += rw.y; s4.z += rw.z; s4.w += rw.w;
    }
    // coalesced partial store (no atomics)
    *reinterpret_cast<float4*>(
        upper_ptr(Pb, (it & 1) * 1048576 + ms * 32768 + (b << 10) + 4 * tid)) = s4;
}

// ---------------------------------------------------------------------------
// Kernel 3b (once): v5 = f(sum of buffer-0 partials), for p_pass.
// ---------------------------------------------------------------------------
__global__ __launch_bounds__(256)
void v_final_kernel(float* __restrict__ Pb, float* __restrict__ v,
                    const float* __restrict__ lp, const float* __restrict__ rp)
{
    const int t = blockIdx.x * 256 + threadIdx.x;   // 0..32767 = b*1024+n
    const float l = lp[0], rho = rp[0];
    const float fi = rho / fmaxf(rho + l, 1e-8f);
    float s = 0.f;
    #pragma unroll
    for (int ms = 0; ms < 32; ++ms)
        s += *upper_ptr(Pb, ms * 32768 + t);        // it=4 wrote buffer X=0
    v[t] = __powf((1.0f / 1024.0f) / fmaxf(s * (1.0f / 65535.0f), 1e-8f), fi);
}

// ---------------------------------------------------------------------------
// Kernel 4: P = u*K*v (u16 K lower half-slot -> fp32 P full slot), row sums,
// weighted_ref. (unchanged from R2, proven)
// ---------------------------------------------------------------------------
__global__ __launch_bounds__(256)
void p_pass_kernel(float* __restrict__ Kmat, const float* __restrict__ u,
                   const float* __restrict__ v, const float* __restrict__ tgt,
                   float* __restrict__ rowb, float* __restrict__ wref)
{
    const int gid  = (blockIdx.x * 256 + threadIdx.x) >> 6;
    const int lane = threadIdx.x & 63;
    const int b = gid >> 10;
    char* rowbase = (char*)Kmat + ((size_t)gid << 12);
    const uint4* kr = (const uint4*)rowbase;
    uint4 ku[2];
    ku[0] = kr[lane];
    ku[1] = kr[64 + lane];
    const float4* vb = (const float4*)(v + (b << 10));
    const float4* tb = (const float4*)(tgt + (size_t)b * 3072);
    const float um_s = u[gid] * (1.0f / 65535.0f);
    float4 vv[4], txa[4], tya[4], tza[4];
    vv[0]  = vb[2 * lane];        vv[1]  = vb[2 * lane + 1];
    vv[2]  = vb[128 + 2 * lane];  vv[3]  = vb[129 + 2 * lane];
    txa[0] = tb[2 * lane];        txa[1] = tb[2 * lane + 1];
    txa[2] = tb[128 + 2 * lane];  txa[3] = tb[129 + 2 * lane];
    tya[0] = tb[256 + 2 * lane];  tya[1] = tb[257 + 2 * lane];
    tya[2] = tb[384 + 2 * lane];  tya[3] = tb[385 + 2 * lane];
    tza[0] = tb[512 + 2 * lane];  tza[1] = tb[513 + 2 * lane];
    tza[2] = tb[640 + 2 * lane];  tza[3] = tb[641 + 2 * lane];
    asm volatile("s_waitcnt vmcnt(0)" ::: "memory");
    float4* prow = (float4*)rowbase;
    float s = 0.f, x = 0.f, y = 0.f, z = 0.f;
    #pragma unroll
    for (int c = 0; c < 2; ++c) {
        const uint4 q = ku[c];
        const float k0 = (float)(q.x & 0xffffu), k1 = (float)(q.x >> 16);
        const float k2 = (float)(q.y & 0xffffu), k3 = (float)(q.y >> 16);
        const float k4 = (float)(q.z & 0xffffu), k5 = (float)(q.z >> 16);
        const float k6 = (float)(q.w & 0xffffu), k7 = (float)(q.w >> 16);
        const float4 va = vv[2 * c], vb2 = vv[2 * c + 1];
        float4 pa, pb;
        pa.x = um_s * k0 * va.x;  pa.y = um_s * k1 * va.y;
        pa.z = um_s * k2 * va.z;  pa.w = um_s * k3 * va.w;
        pb.x = um_s * k4 * vb2.x; pb.y = um_s * k5 * vb2.y;
        pb.z = um_s * k6 * vb2.z; pb.w = um_s * k7 * vb2.w;
        prow[c * 128 + 2 * lane]     = pa;
        prow[c * 128 + 2 * lane + 1] = pb;
        s += (pa.x + pa.y) + (pa.z + pa.w) + (pb.x + pb.y) + (pb.z + pb.w);
        const float4 x0 = txa[2 * c], x1 = txa[2 * c + 1];
        const float4 y0 = tya[2 * c], y1 = tya[2 * c + 1];
        const float4 z0 = tza[2 * c], z1 = tza[2 * c + 1];
        x = fmaf(pa.x, x0.x, x); x = fmaf(pa.y, x0.y, x);
        x = fmaf(pa.z, x0.z, x); x = fmaf(pa.w, x0.w, x);
        x = fmaf(pb.x, x1.x, x); x = fmaf(pb.y, x1.y, x);
        x = fmaf(pb.z, x1.z, x); x = fmaf(pb.w, x1.w, x);
        y = fmaf(pa.x, y0.x, y); y = fmaf(pa.y, y0.y, y);
        y = fmaf(pa.z, y0.z, y); y = fmaf(pa.w, y0.w, y);
        y = fmaf(pb.x, y1.x, y); y = fmaf(pb.y, y1.y, y);
        y = fmaf(pb.z, y1.z, y); y = fmaf(pb.w, y1.w, y);
        z = fmaf(pa.x, z0.x, z); z = fmaf(pa.y, z0.y, z);
        z = fmaf(pa.z, z0.z, z); z = fmaf(pa.w, z0.w, z);
        z = fmaf(pb.x, z1.x, z); z = fmaf(pb.y, z1.y, z);
        z = fmaf(pb.z, z1.z, z); z = fmaf(pb.w, z1.w, z);
    }
    #pragma unroll
    for (int off = 32; off > 0; off >>= 1) {
        s += __shfl_down(s, off);
        x += __shfl_down(x, off);
        y += __shfl_down(y, off);
        z += __shfl_down(z, off);
    }
    if (lane == 0) {
        rowb[gid] = s;
        const float inv = 1.0f / (s + 1e-6f);
        wref[gid * 3 + 0] = x * inv;
        wref[gid * 3 + 1] = y * inv;
        wref[gid * 3 + 2] = z * inv;
    }
}

// ---------------------------------------------------------------------------
// Kernel 5: per-batch weighted centroids + covariance (one block per batch)
// ---------------------------------------------------------------------------
__device__ __forceinline__ float block_reduce_sum(float x, float* lds4, int wv, int lane)
{
    #pragma unroll
    for (int off = 32; off > 0; off >>= 1) x += __shfl_down(x, off);
    __syncthreads();
    if (lane == 0) lds4[wv] = x;
    __syncthreads();
    return (lds4[0] + lds4[1]) + (lds4[2] + lds4[3]);
}

__global__ __launch_bounds__(256)
void kabsch_stats_kernel(const float* __restrict__ rowb, const float* __restrict__ wref,
                         const float* __restrict__ src, float* __restrict__ cov,
                         float* __restrict__ ca, float* __restrict__ cb)
{
    __shared__ float lds4[4];
    const int b = blockIdx.x, tid = threadIdx.x;
    const int wv = tid >> 6, lane = tid & 63;
    float r[4], w[4], ax[4], ay[4], az[4], bx[4], by[4], bz[4];
    float rsum = 0.f;
    #pragma unroll
    for (int i = 0; i < 4; ++i) {
        const int m = tid + 256 * i;
        r[i] = rowb[(b << 10) + m];
        rsum += r[i];
    }
    const float total = block_reduce_sum(rsum, lds4, wv, lane);
    const float inv = 1.0f / (total + 1e-6f);
    #pragma unroll
    for (int i = 0; i < 4; ++i) {
        const int m = tid + 256 * i;
        w[i]  = r[i] * inv;
        ax[i] = src[b * 3072 + m];
        ay[i] = src[b * 3072 + 1024 + m];
        az[i] = src[b * 3072 + 2048 + m];
        bx[i] = wref[((b << 10) + m) * 3 + 0];
        by[i] = wref[((b << 10) + m) * 3 + 1];
        bz[i] = wref[((b << 10) + m) * 3 + 2];
    }
    float cax = 0, cay = 0, caz = 0, cbx = 0, cby = 0, cbz = 0;
    #pragma unroll
    for (int i = 0; i < 4; ++i) {
        cax = fmaf(ax[i], w[i], cax); cay = fmaf(ay[i], w[i], cay); caz = fmaf(az[i], w[i], caz);
        cbx = fmaf(bx[i], w[i], cbx); cby = fmaf(by[i], w[i], cby); cbz = fmaf(bz[i], w[i], cbz);
    }
    cax = block_reduce_sum(cax, lds4, wv, lane);
    cay = block_reduce_sum(cay, lds4, wv, lane);
    caz = block_reduce_sum(caz, lds4, wv, lane);
    cbx = block_reduce_sum(cbx, lds4, wv, lane);
    cby = block_reduce_sum(cby, lds4, wv, lane);
    cbz = block_reduce_sum(cbz, lds4, wv, lane);
    float c[9] = {0,0,0,0,0,0,0,0,0};
    #pragma unroll
    for (int i = 0; i < 4; ++i) {
        const float dax = ax[i] - cax, day = ay[i] - cay, daz = az[i] - caz;
        const float dbx = (bx[i] - cbx) * w[i];
        const float dby = (by[i] - cby) * w[i];
        const float dbz = (bz[i] - cbz) * w[i];
        c[0] = fmaf(dax, dbx, c[0]); c[1] = fmaf(dax, dby, c[1]); c[2] = fmaf(dax, dbz, c[2]);
        c[3] = fmaf(day, dbx, c[3]); c[4] = fmaf(day, dby, c[4]); c[5] = fmaf(day, dbz, c[5]);
        c[6] = fmaf(daz, dbx, c[6]); c[7] = fmaf(daz, dby, c[7]); c[8] = fmaf(daz, dbz, c[8]);
    }
    #pragma unroll
    for (int k = 0; k < 9; ++k) c[k] = block_reduce_sum(c[k], lds4, wv, lane);
    if (tid == 0) {
        #pragma unroll
        for (int k = 0; k < 9; ++k) cov[b * 9 + k] = c[k];
        ca[b * 3 + 0] = cax; ca[b * 3 + 1] = cay; ca[b * 3 + 2] = caz;
        cb[b * 3 + 0] = cbx; cb[b * 3 + 1] = cby; cb[b * 3 + 2] = cbz;
    }
}

// ---------------------------------------------------------------------------
// Kernel 6: 3x3 SVD (double-precision Jacobi on A^T A) + Kabsch R,t
// ---------------------------------------------------------------------------
__device__ __forceinline__ void jrot_d(double S[3][3], double V[3][3], int p, int q)
{
    const double apq = S[p][q];
    if (fabs(apq) < 1e-300) return;
    const double theta = (S[q][q] - S[p][p]) / (2.0 * apq);
    const double tt = copysign(1.0, theta) / (fabs(theta) + sqrt(1.0 + theta * theta));
    const double c = 1.0 / sqrt(1.0 + tt * tt);
    const double s = tt * c;
    #pragma unroll
    for (int k = 0; k < 3; ++k) {
        const double skp = S[k][p], skq = S[k][q];
        S[k][p] = c * skp - s * skq;
        S[k][q] = s * skp + c * skq;
    }
    #pragma unroll
    for (int k = 0; k < 3; ++k) {
        const double spk = S[p][k], sqk = S[q][k];
        S[p][k] = c * spk - s * sqk;
        S[q][k] = s * spk + c * sqk;
    }
    #pragma unroll
    for (int k = 0; k < 3; ++k) {
        const double vkp = V[k][p], vkq = V[k][q];
        V[k][p] = c * vkp - s * vkq;
        V[k][q] = s * vkp + c * vkq;
    }
}

__global__ __launch_bounds__(64)
void svd_kernel(const float* __restrict__ cov, const float* __restrict__ ca,
                const float* __restrict__ cb, float* __restrict__ out)
{
    const int b = threadIdx.x;
    if (b >= 32) return;
    double A[3][3];
    #pragma unroll
    for (int i = 0; i < 3; ++i)
        #pragma unroll
        for (int j = 0; j < 3; ++j)
            A[i][j] = (double)cov[b * 9 + i * 3 + j];
    double S[3][3];
    #pragma unroll
    for (int i = 0; i < 3; ++i)
        #pragma unroll
        for (int j = 0; j < 3; ++j)
            S[i][j] = A[0][i] * A[0][j] + A[1][i] * A[1][j] + A[2][i] * A[2][j];
    double V[3][3] = {{1,0,0},{0,1,0},{0,0,1}};
    for (int sweep = 0; sweep < 8; ++sweep) {
        jrot_d(S, V, 0, 1);
        jrot_d(S, V, 0, 2);
        jrot_d(S, V, 1, 2);
    }
    int o0 = 0, o1 = 1, o2 = 2;
    double e0 = S[0][0], e1 = S[1][1], e2 = S[2][2];
    double tf; int ti;
    if (e0 < e1) { tf = e0; e0 = e1; e1 = tf; ti = o0; o0 = o1; o1 = ti; }
    if (e0 < e2) { tf = e0; e0 = e2; e2 = tf; ti = o0; o0 = o2; o2 = ti; }
    if (e1 < e2) { tf = e1; e1 = e2; e2 = tf; ti = o1; o1 = o2; o2 = ti; }
    double v1[3] = {V[0][o0], V[1][o0], V[2][o0]};
    double v2[3] = {V[0][o1], V[1][o1], V[2][o1]};
    double v3[3] = {V[0][o2], V[1][o2], V[2][o2]};
    double Av1[3], Av2[3];
    #pragma unroll
    for (int i = 0; i < 3; ++i) {
        Av1[i] = A[i][0] * v1[0] + A[i][1] * v1[1] + A[i][2] * v1[2];
        Av2[i] = A[i][0] * v2[0] + A[i][1] * v2[1] + A[i][2] * v2[2];
    }
    const double n1 = sqrt(Av1[0]*Av1[0] + Av1[1]*Av1[1] + Av1[2]*Av1[2]);
    const double in1 = 1.0 / fmax(n1, 1e-300);
    double u1[3] = {Av1[0]*in1, Av1[1]*in1, Av1[2]*in1};
    const double d12 = Av2[0]*u1[0] + Av2[1]*u1[1] + Av2[2]*u1[2];
    double u2[3] = {Av2[0] - d12*u1[0], Av2[1] - d12*u1[1], Av2[2] - d12*u1[2]};
    const double n2 = sqrt(u2[0]*u2[0] + u2[1]*u2[1] + u2[2]*u2[2]);
    const double in2 = 1.0 / fmax(n2, 1e-300);
    u2[0] *= in2; u2[1] *= in2; u2[2] *= in2;
    double u3[3] = {u1[1]*u2[2] - u1[2]*u2[1],
                    u1[2]*u2[0] - u1[0]*u2[2],
                    u1[0]*u2[1] - u1[1]*u2[0]};
    double R0[3][3];
    #pragma unroll
    for (int i = 0; i < 3; ++i)
        #pragma unroll
        for (int j = 0; j < 3; ++j)
            R0[i][j] = v1[i]*u1[j] + v2[i]*u2[j] + v3[i]*u3[j];
    const double det =
        R0[0][0]*(R0[1][1]*R0[2][2] - R0[1][2]*R0[2][1])
      - R0[0][1]*(R0[1][0]*R0[2][2] - R0[1][2]*R0[2][0])
      + R0[0][2]*(R0[1][0]*R0[2][1] - R0[1][1]*R0[2][0]);
    double Rm[3][3];
    if (det > 0.0) {
        #pragma unroll
        for (int i = 0; i < 3; ++i)
            #pragma unroll
            for (int j = 0; j < 3; ++j)
                Rm[i][j] = R0[i][j];
    } else {
        #pragma unroll
        for (int i = 0; i < 3; ++i)
            #pragma unroll
            for (int j = 0; j < 3; ++j)
                Rm[i][j] = R0[i][j] - 2.0 * v3[i] * u3[j];
    }
    const double cax = (double)ca[b*3+0], cay = (double)ca[b*3+1], caz = (double)ca[b*3+2];
    #pragma unroll
    for (int i = 0; i < 3; ++i)
        #pragma unroll
        for (int j = 0; j < 3; ++j)
            out[b * 9 + i * 3 + j] = (float)Rm[i][j];
    #pragma unroll
    for (int i = 0; i < 3; ++i)
        out[288 + b * 3 + i] = (float)((double)cb[b*3+i] - (Rm[i][0]*cax + Rm[i][1]*cay + Rm[i][2]*caz));
}

// ---------------------------------------------------------------------------
extern "C" void kernel_launch(void* const* d_in, const int* in_sizes, int n_in,
                              void* d_out, int out_size, void* d_ws, size_t ws_size,
                              hipStream_t stream)
{
    const float* srcE = (const float*)d_in[0];
    const float* tgtE = (const float*)d_in[1];
    const float* src  = (const float*)d_in[2];
    const float* tgt  = (const float*)d_in[3];
    const float* lp   = (const float*)d_in[4];
    const float* rp   = (const float*)d_in[5];
    float* out  = (float*)d_out;                 // R(288) | t(96) | P(32M)
    float* Pout = out + 384;

    float* ws   = (float*)d_ws;
    float* w1   = ws;            // 32768
    float* w2   = ws + 32768;    // 32768
    float* u    = ws + 65536;    // 32768
    float* v    = ws + 98304;    // 32768
    float* rowb = ws + 131072;   // 32768
    float* wref = ws + 163840;   // 98304
    float* cov  = ws + 262144;   // 288
    float* ca   = ws + 262432;   // 96
    float* cb   = ws + 262528;   // 96

    prep_kernel<<<dim3(16, 2, 32), 256, 0, stream>>>(srcE, tgtE, w1, w2, Pout);
    gemm_kexp_kernel<<<dim3(8, 8, 32), 256, 0, stream>>>(w1, w2, lp, Pout);
    for (int it = 0; it < 5; ++it)
        sink_iter_kernel<<<dim3(32, 32), 256, 0, stream>>>(Pout, u, lp, rp, it);
    v_final_kernel<<<128, 256, 0, stream>>>(Pout, v, lp, rp);
    p_pass_kernel<<<8192, 256, 0, stream>>>(Pout, u, v, tgt, rowb, wref);
    kabsch_stats_kernel<<<32, 256, 0, stream>>>(rowb, wref, src, cov, ca, cb);
    svd_kernel<<<1, 64, 0, stream>>>(cov, ca, cb, out);
}